// Round 11
// baseline (593.202 us; speedup 1.0000x reference)
//
#include <hip/hip_runtime.h>
#include <hip/hip_bf16.h>
#include <math.h>

#define NN 8192
#define DD 512
#define INV_T 14.285714285714286f   // 1/0.07 ; also the logits_max (diagonal) value

typedef __attribute__((ext_vector_type(8))) short s16x8;  // 8 bf16 = 4 VGPRs
typedef __attribute__((ext_vector_type(4))) float f32x4;
typedef __attribute__((ext_vector_type(4))) int   i32x4;

__device__ __forceinline__ unsigned short f32_to_bf16(float f) {
  unsigned int u = __float_as_uint(f);
  u += 0x7FFFu + ((u >> 16) & 1u);   // round-to-nearest-even
  return (unsigned short)(u >> 16);
}

__device__ __forceinline__ void async16(const void* g, void* l) {
  // 16B-wide global->LDS DMA; LDS dest must be wave-uniform base + lane*16
  __builtin_amdgcn_global_load_lds((__attribute__((address_space(1))) void*)(void*)g,
                                   (__attribute__((address_space(3))) void*)l,
                                   16, 0, 0);
}

// ---------------- Kernel A: normalize rows, emit bf16 ----------------
__global__ __launch_bounds__(256) void normalize_kernel(const float* __restrict__ f,
                                                        unsigned short* __restrict__ fnb) {
  const int wave = threadIdx.x >> 6;
  const int lane = threadIdx.x & 63;
  const int row  = blockIdx.x * 4 + wave;
  const float* src = f + (size_t)row * DD + lane * 8;
  float4 v0 = *(const float4*)src;
  float4 v1 = *(const float4*)(src + 4);
  float ss = v0.x*v0.x + v0.y*v0.y + v0.z*v0.z + v0.w*v0.w
           + v1.x*v1.x + v1.y*v1.y + v1.z*v1.z + v1.w*v1.w;
  #pragma unroll
  for (int o = 32; o; o >>= 1) ss += __shfl_xor(ss, o);
  const float r = 1.0f / fmaxf(sqrtf(ss), 1e-8f);
  ushort4 a, b;
  a.x = f32_to_bf16(v0.x * r); a.y = f32_to_bf16(v0.y * r);
  a.z = f32_to_bf16(v0.z * r); a.w = f32_to_bf16(v0.w * r);
  b.x = f32_to_bf16(v1.x * r); b.y = f32_to_bf16(v1.y * r);
  b.z = f32_to_bf16(v1.z * r); b.w = f32_to_bf16(v1.w * r);
  unsigned short* dst = fnb + (size_t)row * DD + lane * 8;
  *(ushort4*)dst = a;
  *(ushort4*)(dst + 4) = b;
}

// ---------------- Kernel B: wave-specialized fused kernel ----------------
// 512 threads: waves 0-3 = GEMM (R8's LDS-staged 128x128 tile, natural B),
// waves 4-7 = mask producers. Mask waves stream the block's 256 KB of masks
// (int4 loads), ballot-compress to R8's bit convention, write 8 KB LDS bit
// tiles. Barrier-pinned distance-1 pipeline with EXACTLY 32 barriers matching
// the K-loop's 32 -> GEMM MFMA/L2-staging and mask HBM stream overlap on the
// CU (m114). After common barrier #33, GEMM waves run R8's bit epilogue
// (LDS-only) + LDS accum; barrier #34; one batch of global atomics.
__global__ __launch_bounds__(512, 4) void fused_kernel(const unsigned short* __restrict__ fnb,
                                                       const int* __restrict__ posm,
                                                       const int* __restrict__ negm,
                                                       float* __restrict__ Spos,
                                                       float* __restrict__ Sneg,
                                                       float* __restrict__ Pcnt) {
  // decode compact triangular block id -> (bi, bj), bi <= bj, 64x64 block grid
  const int bid = blockIdx.x;
  int bi = (int)(64.5 - sqrt(64.5 * 64.5 - 2.0 * (double)bid));
  while (64 * bi - bi * (bi - 1) / 2 > bid) --bi;
  while (64 * (bi + 1) - (bi + 1) * bi / 2 <= bid) ++bi;
  const int bj = bi + (bid - (64 * bi - bi * (bi - 1) / 2));
  const int I = bi * 128;
  const int J = bj * 128;
  const bool offdiag = (bi != bj);

  const int tid  = threadIdx.x;
  const int wave = tid >> 6;
  const int lane = tid & 63;

  __shared__ alignas(16) unsigned short lA[128 * 32];          // 8 KB
  __shared__ alignas(16) unsigned short lB[128 * 32];          // 8 KB
  __shared__ unsigned long long bdir[2][128][2];               // 4 KB bit tiles
  __shared__ unsigned long long btr [2][128][2];               // 4 KB
  __shared__ float sacc[2][128][3];                            // 3 KB
  for (int t = tid; t < 2 * 128 * 3; t += 512) ((float*)sacc)[t] = 0.f;

  f32x4 acc[4][4];

  if (wave < 4) {
    // ================= GEMM role (R8-proven) =================
    const int wm = wave >> 1, wn = wave & 1;
    const int q = lane >> 4, c16 = lane & 15;
    const f32x4 z4 = {0.f, 0.f, 0.f, 0.f};
    #pragma unroll
    for (int mt = 0; mt < 4; ++mt)
      #pragma unroll
      for (int nt = 0; nt < 4; ++nt) acc[mt][nt] = z4;

    for (int kk = 0; kk < DD / 32; ++kk) {
      const int k0 = kk * 32;
      #pragma unroll
      for (int c = 0; c < 2; ++c) {
        const int fidx = tid + c * 256;        // GEMM tids are 0..255
        const int row  = fidx >> 2;
        const int p    = fidx & 3;
        const int csrc = (p ^ ((row >> 1) & 3)) & 3;   // XOR swizzle (global side)
        async16(fnb + (size_t)(I + row) * DD + k0 + csrc * 8, (char*)lA + fidx * 16);
        async16(fnb + (size_t)(J + row) * DD + k0 + csrc * 8, (char*)lB + fidx * 16);
      }
      __syncthreads();                         // barriers 1..32 (odd)

      s16x8 aF[4], bF[4];
      #pragma unroll
      for (int t = 0; t < 4; ++t) {
        const int arow = wm * 64 + t * 16 + c16;
        const int apos = (q ^ ((arow >> 1) & 3)) & 3;
        aF[t] = *(const s16x8*)((const char*)lA + arow * 64 + apos * 16);
        const int brow = wn * 64 + t * 16 + c16;
        const int bpos = (q ^ ((brow >> 1) & 3)) & 3;
        bF[t] = *(const s16x8*)((const char*)lB + brow * 64 + bpos * 16);
      }
      #pragma unroll
      for (int mt = 0; mt < 4; ++mt)
        #pragma unroll
        for (int nt = 0; nt < 4; ++nt)
          acc[mt][nt] = __builtin_amdgcn_mfma_f32_16x16x32_bf16(aF[mt], bF[nt], acc[mt][nt], 0, 0, 0);
      __syncthreads();                         // barriers 1..32 (even)
    }
    // exp in place (overlaps mask-wave tail)
    #pragma unroll
    for (int mt = 0; mt < 4; ++mt)
      #pragma unroll
      for (int nt = 0; nt < 4; ++nt)
        #pragma unroll
        for (int r = 0; r < 4; ++r)
          acc[mt][nt][r] = __expf(acc[mt][nt][r] * INV_T - INV_T);
  } else {
    // ================= mask-producer role =================
    // wave mw: msel = mw&1 (pos/neg), half = mw>>1 (rows 0-63 / 64-127).
    // 32 groups: g<16 direct tile (rows I.., cols J..), g>=16 transposed
    // (rows J.., cols I..). Group g covers 4 tile rows: half*64+(g&15)*4+2u+sub.
    // Distance-1 pipeline pinned by the 32 barriers.
    const int mw   = wave - 4;
    const int msel = mw & 1;
    const int half = mw >> 1;
    const int* mb  = msel ? negm : posm;
    const int sub  = lane >> 5;          // row parity within pair
    const int col4 = (lane & 31) * 4;

    i32x4 vbuf[2][2];                    // [g&1][u]

    #define MLOAD(g)                                                          \
      if ((g) < 32 && !((g) >= 16 && !offdiag)) {                             \
        const int R0 = ((g) < 16) ? I : J;                                    \
        const int C0 = ((g) < 16) ? J : I;                                    \
        _Pragma("unroll")                                                     \
        for (int u = 0; u < 2; ++u) {                                         \
          const int rl = half * 64 + ((g) & 15) * 4 + 2 * u + sub;            \
          vbuf[(g) & 1][u] = __builtin_nontemporal_load(                      \
              (const i32x4*)(mb + (size_t)(R0 + rl) * NN + C0 + col4));       \
        }                                                                     \
      }

    MLOAD(0)
    #pragma unroll
    for (int g = 0; g < 32; ++g) {
      MLOAD(g + 1)                       // issued BEFORE the barrier: cannot sink
      __syncthreads();                   // barriers 1..32
      if (!(g >= 16 && !offdiag)) {
        unsigned long long (*dst)[2] = (g < 16) ? bdir[msel] : btr[msel];
        #pragma unroll
        for (int u = 0; u < 2; ++u) {
          const i32x4 v = vbuf[g & 1][u];
          const unsigned long long b0 = __ballot(v.x != 0);
          const unsigned long long b1 = __ballot(v.y != 0);
          const unsigned long long b2 = __ballot(v.z != 0);
          const unsigned long long b3 = __ballot(v.w != 0);
          if (lane < 4) {                // lane w -> word (s = w>>1, h = w&1)
            const int s = lane >> 1, h = lane & 1;
            const int k = 16 * (2 * s + h);
            const unsigned long long t =
                ((b0 >> k) & 0xFFFFull)         | (((b1 >> k) & 0xFFFFull) << 16)
              | (((b2 >> k) & 0xFFFFull) << 32) | (((b3 >> k) & 0xFFFFull) << 48);
            dst[half * 64 + (g & 15) * 4 + 2 * u + s][h] = t;
          }
        }
      }
    }
  }

  __syncthreads();   // #33: bit tiles complete, visible to GEMM waves

  if (wave < 4) {
    // ================= R8 bit epilogue (LDS-only reads) =================
    const int wm = wave >> 1, wn = wave & 1;
    const int q = lane >> 4, c16 = lane & 15;
    const bool hasdiag = (bi == bj) && (wm == wn);

    const int shd = (c16 >> 2) + (c16 & 3) * 16;
    #pragma unroll
    for (int mt = 0; mt < 4; ++mt) {
      const int rl = wm * 64 + mt * 16 + q * 4;
      #pragma unroll
      for (int r = 0; r < 4; ++r) {
        unsigned long long wp = bdir[0][rl + r][wn];
        unsigned long long wnn = bdir[1][rl + r][wn];
        if (hasdiag) {   // clear own diagonal bit: col64 = mt*16+q*4+r
          const unsigned long long m = ~(1ULL << (mt * 4 + q + 16 * r));
          wp &= m; wnn &= m;
        }
        float dsp = 0.f, dsn = 0.f;
        #pragma unroll
        for (int nt = 0; nt < 4; ++nt) {
          const float e = acc[mt][nt][r];
          dsp = fmaf(e, (float)((wp  >> (nt * 4 + shd)) & 1ULL), dsp);
          dsn = fmaf(e, (float)((wnn >> (nt * 4 + shd)) & 1ULL), dsn);
        }
        #pragma unroll
        for (int o = 1; o <= 8; o <<= 1) {
          dsp += __shfl_xor(dsp, o);
          dsn += __shfl_xor(dsn, o);
        }
        if (c16 == 0) {
          atomicAdd(&sacc[0][rl + r][0], dsp);
          atomicAdd(&sacc[0][rl + r][1], dsn);
          atomicAdd(&sacc[0][rl + r][2], (float)__popcll(wp));
        }
      }
    }
    if (offdiag) {
      #pragma unroll
      for (int nt = 0; nt < 4; ++nt) {
        const int cl = wn * 64 + nt * 16 + c16;
        const unsigned long long tpw = btr[0][cl][wm];
        const unsigned long long tnw = btr[1][cl][wm];
        float ts = 0.f, tn = 0.f;
        #pragma unroll
        for (int mt = 0; mt < 4; ++mt) {
          const int sh = mt * 4 + q;
          #pragma unroll
          for (int r = 0; r < 4; ++r) {
            const float e = acc[mt][nt][r];
            ts = fmaf(e, (float)((tpw >> (sh + 16 * r)) & 1ULL), ts);
            tn = fmaf(e, (float)((tnw >> (sh + 16 * r)) & 1ULL), tn);
          }
        }
        ts += __shfl_xor(ts, 16); ts += __shfl_xor(ts, 32);
        tn += __shfl_xor(tn, 16); tn += __shfl_xor(tn, 32);
        if (q == 0) {
          atomicAdd(&sacc[1][cl][0], ts);
          atomicAdd(&sacc[1][cl][1], tn);
          atomicAdd(&sacc[1][cl][2], (float)__popcll(tpw));
        }
      }
    }
  }

  __syncthreads();   // #34: sacc complete

  // one batch of global atomics; nothing waits on them
  const int r = tid & 127;
  if (tid < 128) {
    atomicAdd(&Spos[I + r], sacc[0][r][0]);
    atomicAdd(&Sneg[I + r], sacc[0][r][1]);
    atomicAdd(&Pcnt[I + r], sacc[0][r][2]);
  } else if (tid < 256 && offdiag) {
    atomicAdd(&Spos[J + r], sacc[1][r][0]);
    atomicAdd(&Sneg[J + r], sacc[1][r][1]);
    atomicAdd(&Pcnt[J + r], sacc[1][r][2]);
  }
}

// ---------------- Kernel C: finalize ----------------
__global__ __launch_bounds__(256) void finalize_kernel(const float* __restrict__ Spos,
                                                       const float* __restrict__ Sneg,
                                                       const float* __restrict__ Pcnt,
                                                       float* __restrict__ out) {
  float local = 0.f;
  for (int i = threadIdx.x; i < NN; i += 256) {
    const float sp = Spos[i], sn = Sneg[i], pc = Pcnt[i];
    const float card = (pc == 0.f) ? 1.f : pc;
    local += (logf(sn) * pc - sp) / card;
  }
  #pragma unroll
  for (int o = 32; o; o >>= 1) local += __shfl_xor(local, o);
  __shared__ float red[4];
  if ((threadIdx.x & 63) == 0) red[threadIdx.x >> 6] = local;
  __syncthreads();
  if (threadIdx.x == 0)
    out[0] = (red[0] + red[1] + red[2] + red[3]) * (1.0f / (float)NN);
}

extern "C" void kernel_launch(void* const* d_in, const int* in_sizes, int n_in,
                              void* d_out, int out_size, void* d_ws, size_t ws_size,
                              hipStream_t stream) {
  const float* feat = (const float*)d_in[0];
  const int* posm   = (const int*)d_in[1];
  const int* negm   = (const int*)d_in[2];
  float* out = (float*)d_out;

  char* ws = (char*)d_ws;
  unsigned short* fnb = (unsigned short*)ws;                 // 8 MB
  float* Spos = (float*)(ws + (size_t)8 * 1024 * 1024);
  float* Sneg = Spos + NN;
  float* Pcnt = Sneg + NN;

  hipMemsetAsync(Spos, 0, 3 * NN * sizeof(float), stream);
  normalize_kernel<<<NN / 4, 256, 0, stream>>>(feat, fnb);
  fused_kernel<<<2080, 512, 0, stream>>>(fnb, posm, negm, Spos, Sneg, Pcnt);
  finalize_kernel<<<1, 256, 0, stream>>>(Spos, Sneg, Pcnt, out);
}

// Round 12
// 553.984 us; speedup vs baseline: 1.0708x; 1.0708x over previous
//
#include <hip/hip_runtime.h>
#include <hip/hip_bf16.h>
#include <math.h>

#define NN 8192
#define DD 512
#define INV_T 14.285714285714286f   // 1/0.07 ; also the logits_max (diagonal) value

typedef __attribute__((ext_vector_type(8))) short s16x8;  // 8 bf16 = 4 VGPRs
typedef __attribute__((ext_vector_type(4))) float f32x4;
typedef __attribute__((ext_vector_type(4))) int   i32x4;

__device__ __forceinline__ unsigned short f32_to_bf16(float f) {
  unsigned int u = __float_as_uint(f);
  u += 0x7FFFu + ((u >> 16) & 1u);   // round-to-nearest-even
  return (unsigned short)(u >> 16);
}

__device__ __forceinline__ void async16(const void* g, void* l) {
  // 16B-wide global->LDS DMA; LDS dest must be wave-uniform base + lane*16
  __builtin_amdgcn_global_load_lds((__attribute__((address_space(1))) void*)(void*)g,
                                   (__attribute__((address_space(3))) void*)l,
                                   16, 0, 0);
}

// ---------------- Kernel A: normalize rows, emit bf16 ----------------
__global__ __launch_bounds__(256) void normalize_kernel(const float* __restrict__ f,
                                                        unsigned short* __restrict__ fnb) {
  const int wave = threadIdx.x >> 6;
  const int lane = threadIdx.x & 63;
  const int row  = blockIdx.x * 4 + wave;
  const float* src = f + (size_t)row * DD + lane * 8;
  float4 v0 = *(const float4*)src;
  float4 v1 = *(const float4*)(src + 4);
  float ss = v0.x*v0.x + v0.y*v0.y + v0.z*v0.z + v0.w*v0.w
           + v1.x*v1.x + v1.y*v1.y + v1.z*v1.z + v1.w*v1.w;
  #pragma unroll
  for (int o = 32; o; o >>= 1) ss += __shfl_xor(ss, o);
  const float r = 1.0f / fmaxf(sqrtf(ss), 1e-8f);
  ushort4 a, b;
  a.x = f32_to_bf16(v0.x * r); a.y = f32_to_bf16(v0.y * r);
  a.z = f32_to_bf16(v0.z * r); a.w = f32_to_bf16(v0.w * r);
  b.x = f32_to_bf16(v1.x * r); b.y = f32_to_bf16(v1.y * r);
  b.z = f32_to_bf16(v1.z * r); b.w = f32_to_bf16(v1.w * r);
  unsigned short* dst = fnb + (size_t)row * DD + lane * 8;
  *(ushort4*)dst = a;
  *(ushort4*)(dst + 4) = b;
}

// ---------------- Kernel B: fused kernel, mask stream inside the K-loop ----------------
// 128x128 tile per block, 4 waves each 64x64 (4x4 of 16x16x32 bf16 MFMA).
// R9's LDS-staged GEMM K-loop (16 iters, 2 barriers each). Each wave ALSO
// streams 1/4 of the block's masks: wave -> (tile in {dir,tr}, msel in
// {pos,neg}); 4 int4 wave-loads per iter issued right after barrier1 (latency
// hides under the 16 MFMA), ballot-compressed to R11's verified bit
// convention and written to 8 KB LDS bit tiles after the MFMA block.
// s_barrier pins issue/drain placement (loads cannot be sunk across it, the
// R5 failure); full K-loop unroll keeps vbuf[2][4] register-resident.
// Epilogue: R11's LDS-only bit epilogue + LDS accum + end-batched atomics.
__global__ __launch_bounds__(256, 2) void fused_kernel(const unsigned short* __restrict__ fnb,
                                                       const int* __restrict__ posm,
                                                       const int* __restrict__ negm,
                                                       float* __restrict__ Spos,
                                                       float* __restrict__ Sneg,
                                                       float* __restrict__ Pcnt) {
  // decode compact triangular block id -> (bi, bj), bi <= bj, 64x64 block grid
  const int bid = blockIdx.x;
  int bi = (int)(64.5 - sqrt(64.5 * 64.5 - 2.0 * (double)bid));
  while (64 * bi - bi * (bi - 1) / 2 > bid) --bi;
  while (64 * (bi + 1) - (bi + 1) * bi / 2 <= bid) ++bi;
  const int bj = bi + (bid - (64 * bi - bi * (bi - 1) / 2));
  const int I = bi * 128;
  const int J = bj * 128;
  const bool offdiag = (bi != bj);

  const int tid  = threadIdx.x;
  const int wave = tid >> 6;
  const int lane = tid & 63;
  const int wm = wave >> 1;            // 0..1 row half
  const int wn = wave & 1;             // 0..1 col half
  const int q   = lane >> 4;           // 0..3
  const int c16 = lane & 15;           // 0..15

  __shared__ alignas(16) unsigned short lA[128 * 32];   // 8 KB
  __shared__ alignas(16) unsigned short lB[128 * 32];   // 8 KB
  __shared__ unsigned long long bdir[2][128][2];        // 4 KB bit tiles
  __shared__ unsigned long long btr [2][128][2];        // 4 KB
  __shared__ float sacc[2][128][3];                     // 3 KB
  for (int t = tid; t < 2 * 128 * 3; t += 256) ((float*)sacc)[t] = 0.f;

  // ---- mask-stream role params (per wave) ----
  const int tile = wave >> 1;          // 0 = direct (rows I, cols J), 1 = transposed
  const int msel = wave & 1;           // 0 = pos, 1 = neg
  const int* mb  = msel ? negm : posm;
  const int R0 = tile ? J : I;
  const int C0 = tile ? I : J;
  const bool do_mask = !(tile && !offdiag);   // diag blocks: transposed tile unused
  const int sub  = lane >> 5;          // row parity within pair
  const int col4 = (lane & 31) * 4;
  const int* mrow = mb + (size_t)R0 * NN + C0 + col4;

  i32x4 vbuf[2][4];                    // [k&1][u] register pipeline buffer

  #define MLOAD(k)                                                            \
    if (do_mask && (k) < 16) {                                                \
      _Pragma("unroll")                                                       \
      for (int u = 0; u < 4; ++u)                                             \
        vbuf[(k) & 1][u] = __builtin_nontemporal_load(                        \
            (const i32x4*)(mrow + (size_t)(8 * (k) + 2 * u + sub) * NN));     \
    }

  #define MDRAIN(k)                                                           \
    if (do_mask) {                                                            \
      unsigned long long (*dst)[2] = tile ? btr[msel] : bdir[msel];           \
      _Pragma("unroll")                                                       \
      for (int u = 0; u < 4; ++u) {                                           \
        const i32x4 v = vbuf[(k) & 1][u];                                     \
        const unsigned long long b0 = __ballot(v.x != 0);                     \
        const unsigned long long b1 = __ballot(v.y != 0);                     \
        const unsigned long long b2 = __ballot(v.z != 0);                     \
        const unsigned long long b3 = __ballot(v.w != 0);                     \
        if (lane < 4) {                                                       \
          const int s = lane >> 1, h = lane & 1;                              \
          const int kb = 16 * (2 * s + h);                                    \
          const unsigned long long t =                                        \
              ((b0 >> kb) & 0xFFFFull)         | (((b1 >> kb) & 0xFFFFull) << 16)  \
            | (((b2 >> kb) & 0xFFFFull) << 32) | (((b3 >> kb) & 0xFFFFull) << 48); \
          dst[8 * (k) + 2 * u + s][h] = t;                                    \
        }                                                                     \
      }                                                                       \
    }

  // ---- GEMM K-loop with interleaved mask stream ----
  f32x4 acc[4][4];
  const f32x4 z4 = {0.f, 0.f, 0.f, 0.f};
  #pragma unroll
  for (int mt = 0; mt < 4; ++mt)
    #pragma unroll
    for (int nt = 0; nt < 4; ++nt) acc[mt][nt] = z4;

  MLOAD(0)

  #pragma unroll
  for (int kk = 0; kk < 16; ++kk) {
    const int k0 = kk * 32;
    #pragma unroll
    for (int c = 0; c < 2; ++c) {
      const int fidx = tid + c * 256;        // 0..511 16B-chunks
      const int row  = fidx >> 2;
      const int p    = fidx & 3;
      const int csrc = (p ^ ((row >> 1) & 3)) & 3;   // XOR swizzle (global side)
      async16(fnb + (size_t)(I + row) * DD + k0 + csrc * 8, (char*)lA + fidx * 16);
      async16(fnb + (size_t)(J + row) * DD + k0 + csrc * 8, (char*)lB + fidx * 16);
    }
    __syncthreads();                   // barrier1: staging (+ prev mask loads) drained

    MLOAD(kk + 1)                      // issue next mask batch; latency hides under MFMA

    s16x8 aF[4], bF[4];
    #pragma unroll
    for (int t = 0; t < 4; ++t) {
      const int arow = wm * 64 + t * 16 + c16;
      const int apos = (q ^ ((arow >> 1) & 3)) & 3;
      aF[t] = *(const s16x8*)((const char*)lA + arow * 64 + apos * 16);
      const int brow = wn * 64 + t * 16 + c16;
      const int bpos = (q ^ ((brow >> 1) & 3)) & 3;
      bF[t] = *(const s16x8*)((const char*)lB + brow * 64 + bpos * 16);
    }
    #pragma unroll
    for (int mt = 0; mt < 4; ++mt)
      #pragma unroll
      for (int nt = 0; nt < 4; ++nt)
        acc[mt][nt] = __builtin_amdgcn_mfma_f32_16x16x32_bf16(aF[mt], bF[nt], acc[mt][nt], 0, 0, 0);

    MDRAIN(kk)                         // ballot data drained at barrier1; bits -> LDS

    __syncthreads();                   // barrier2: LDS safe for next staging
  }

  // exp in place
  #pragma unroll
  for (int mt = 0; mt < 4; ++mt)
    #pragma unroll
    for (int nt = 0; nt < 4; ++nt)
      #pragma unroll
      for (int r = 0; r < 4; ++r)
        acc[mt][nt][r] = __expf(acc[mt][nt][r] * INV_T - INV_T);

  // ---- R11 bit epilogue (LDS-only reads) ----
  const bool hasdiag = (bi == bj) && (wm == wn);
  const int shd = (c16 >> 2) + (c16 & 3) * 16;
  #pragma unroll
  for (int mt = 0; mt < 4; ++mt) {
    const int rl = wm * 64 + mt * 16 + q * 4;
    #pragma unroll
    for (int r = 0; r < 4; ++r) {
      unsigned long long wp  = bdir[0][rl + r][wn];
      unsigned long long wnn = bdir[1][rl + r][wn];
      if (hasdiag) {   // clear own diagonal bit: col64 = mt*16+q*4+r
        const unsigned long long m = ~(1ULL << (mt * 4 + q + 16 * r));
        wp &= m; wnn &= m;
      }
      float dsp = 0.f, dsn = 0.f;
      #pragma unroll
      for (int nt = 0; nt < 4; ++nt) {
        const float e = acc[mt][nt][r];
        dsp = fmaf(e, (float)((wp  >> (nt * 4 + shd)) & 1ULL), dsp);
        dsn = fmaf(e, (float)((wnn >> (nt * 4 + shd)) & 1ULL), dsn);
      }
      #pragma unroll
      for (int o = 1; o <= 8; o <<= 1) {
        dsp += __shfl_xor(dsp, o);
        dsn += __shfl_xor(dsn, o);
      }
      if (c16 == 0) {
        atomicAdd(&sacc[0][rl + r][0], dsp);
        atomicAdd(&sacc[0][rl + r][1], dsn);
        atomicAdd(&sacc[0][rl + r][2], (float)__popcll(wp));
      }
    }
  }
  if (offdiag) {
    #pragma unroll
    for (int nt = 0; nt < 4; ++nt) {
      const int cl = wn * 64 + nt * 16 + c16;
      const unsigned long long tpw = btr[0][cl][wm];
      const unsigned long long tnw = btr[1][cl][wm];
      float ts = 0.f, tn = 0.f;
      #pragma unroll
      for (int mt = 0; mt < 4; ++mt) {
        const int sh = mt * 4 + q;
        #pragma unroll
        for (int r = 0; r < 4; ++r) {
          const float e = acc[mt][nt][r];
          ts = fmaf(e, (float)((tpw >> (sh + 16 * r)) & 1ULL), ts);
          tn = fmaf(e, (float)((tnw >> (sh + 16 * r)) & 1ULL), tn);
        }
      }
      ts += __shfl_xor(ts, 16); ts += __shfl_xor(ts, 32);
      tn += __shfl_xor(tn, 16); tn += __shfl_xor(tn, 32);
      if (q == 0) {
        atomicAdd(&sacc[1][cl][0], ts);
        atomicAdd(&sacc[1][cl][1], tn);
        atomicAdd(&sacc[1][cl][2], (float)__popcll(tpw));
      }
    }
  }

  __syncthreads();

  // one batch of global atomics; nothing waits on them
  const int r = tid & 127;
  if (tid < 128) {
    atomicAdd(&Spos[I + r], sacc[0][r][0]);
    atomicAdd(&Sneg[I + r], sacc[0][r][1]);
    atomicAdd(&Pcnt[I + r], sacc[0][r][2]);
  } else if (offdiag) {
    atomicAdd(&Spos[J + r], sacc[1][r][0]);
    atomicAdd(&Sneg[J + r], sacc[1][r][1]);
    atomicAdd(&Pcnt[J + r], sacc[1][r][2]);
  }
}

// ---------------- Kernel C: finalize ----------------
__global__ __launch_bounds__(256) void finalize_kernel(const float* __restrict__ Spos,
                                                       const float* __restrict__ Sneg,
                                                       const float* __restrict__ Pcnt,
                                                       float* __restrict__ out) {
  float local = 0.f;
  for (int i = threadIdx.x; i < NN; i += 256) {
    const float sp = Spos[i], sn = Sneg[i], pc = Pcnt[i];
    const float card = (pc == 0.f) ? 1.f : pc;
    local += (logf(sn) * pc - sp) / card;
  }
  #pragma unroll
  for (int o = 32; o; o >>= 1) local += __shfl_xor(local, o);
  __shared__ float red[4];
  if ((threadIdx.x & 63) == 0) red[threadIdx.x >> 6] = local;
  __syncthreads();
  if (threadIdx.x == 0)
    out[0] = (red[0] + red[1] + red[2] + red[3]) * (1.0f / (float)NN);
}

extern "C" void kernel_launch(void* const* d_in, const int* in_sizes, int n_in,
                              void* d_out, int out_size, void* d_ws, size_t ws_size,
                              hipStream_t stream) {
  const float* feat = (const float*)d_in[0];
  const int* posm   = (const int*)d_in[1];
  const int* negm   = (const int*)d_in[2];
  float* out = (float*)d_out;

  char* ws = (char*)d_ws;
  unsigned short* fnb = (unsigned short*)ws;                 // 8 MB
  float* Spos = (float*)(ws + (size_t)8 * 1024 * 1024);
  float* Sneg = Spos + NN;
  float* Pcnt = Sneg + NN;

  hipMemsetAsync(Spos, 0, 3 * NN * sizeof(float), stream);
  normalize_kernel<<<NN / 4, 256, 0, stream>>>(feat, fnb);
  fused_kernel<<<2080, 256, 0, stream>>>(fnb, posm, negm, Spos, Sneg, Pcnt);
  finalize_kernel<<<1, 256, 0, stream>>>(Spos, Sneg, Pcnt, out);
}